// Round 6
// baseline (763.091 us; speedup 1.0000x reference)
//
#include <hip/hip_runtime.h>
#include <hip/hip_bf16.h>
#include <type_traits>

typedef __hip_bfloat16 bf16;
typedef __attribute__((ext_vector_type(8))) short s16x8;
typedef __attribute__((ext_vector_type(4))) short s16x4;
typedef __attribute__((ext_vector_type(4))) float f32x4;

#define DEVI __device__ __forceinline__

DEVI float bf2f(bf16 x) { return __bfloat162float(x); }
DEVI float gelu_f(float x) { return 0.5f * x * (1.0f + erff(x * 0.7071067811865476f)); }
DEVI float elu1(float x) { return x > 0.f ? x + 1.f : __expf(x); }  // elu(x)+1
DEVI float s2f(short s) {
  unsigned u = ((unsigned)(unsigned short)s) << 16;
  float f; __builtin_memcpy(&f, &u, 4); return f;
}
DEVI short f2s(float x) {
  bf16 h = __float2bfloat16(x);
  short s; __builtin_memcpy(&s, &h, 2); return s;
}
// runtime-dtype load: isf=1 -> fp32, 0 -> bf16
DEVI float ldd(const void* p, long i, int isf) {
  return isf ? ((const float*)p)[i] : bf2f(((const bf16*)p)[i]);
}

// ---------------- dtype detector ----------------
__global__ void detect_kernel(const void* x0, int* dflag) {
  const int t = threadIdx.x;                  // 64 threads
  const bf16* p = (const bf16*)x0;
  float v = bf2f(p[t * 2]);
  bool ok = (fabsf(v) <= 64.0f);              // false for NaN too
  unsigned long long m = __ballot(ok);
  if (t == 0) dflag[0] = (m == ~0ull) ? 0 : 1;   // 0 = bf16, 1 = fp32
}

// ---------------- bn scale/shift + merge-bias precompute ----------------
// layout: s0[256] t0[256] s1[1024] t1[1024] s2[1024] t2[1024] s3[256] t3[256] mbias[256]
__global__ __launch_bounds__(256) void bnprep_kernel(
    const int* dflag,
    const void* g0, const void* b0, const void* m0, const void* v0,
    const void* g1, const void* b1, const void* m1, const void* v1,
    const void* g2, const void* b2, const void* m2, const void* v2,
    const void* g3, const void* b3, const void* m3, const void* v3,
    const void* mb, float* out)
{
  const int isf = dflag[0];
  int t = threadIdx.x;
  {
    float s = ldd(g0, t, isf) / sqrtf(ldd(v0, t, isf) + 1e-5f);
    out[t] = s; out[256 + t] = ldd(b0, t, isf) - ldd(m0, t, isf) * s;
  }
  for (int i = t; i < 1024; i += 256) {
    float s = ldd(g1, i, isf) / sqrtf(ldd(v1, i, isf) + 1e-5f);
    out[512 + i] = s; out[1536 + i] = ldd(b1, i, isf) - ldd(m1, i, isf) * s;
  }
  for (int i = t; i < 1024; i += 256) {
    float s = ldd(g2, i, isf) / sqrtf(ldd(v2, i, isf) + 1e-5f);
    out[2560 + i] = s; out[3584 + i] = ldd(b2, i, isf) - ldd(m2, i, isf) * s;
  }
  {
    float s = ldd(g3, t, isf) / sqrtf(ldd(v3, t, isf) + 1e-5f);
    out[4608 + t] = s; out[4864 + t] = ldd(b3, t, isf) - ldd(m3, t, isf) * s;
    out[5120 + t] = ldd(mb, t, isf);
  }
}

// ---------------- weight convert to bf16 (concatenated dst) ----------------
// dst elems: [0,65536) qw | kw | vw | mw ... [262144,524288) w1 |
// [524288,786432) w2 | [786432,795648) wdw as [tap][1024] (tap-major!)
// NOTE: rows 0..767 of dst form the concatenated [768][256] qkv weight.
__global__ __launch_bounds__(256) void wconv_kernel(
    const int* dflag,
    const void* qw, const void* kw, const void* vw, const void* mw,
    const void* w1, const void* w2, const void* dw, bf16* dst)
{
  const int isf = dflag[0];
  int i = blockIdx.x * 256 + threadIdx.x;
  if (i >= 795648) return;
  const void* src; int off;
  if (i < 262144) {
    src = (i < 65536) ? qw : (i < 131072) ? kw : (i < 196608) ? vw : mw;
    off = i & 65535;
  } else if (i < 524288) { src = w1; off = i - 262144; }
  else if (i < 786432) { src = w2; off = i - 524288; }
  else {
    src = dw;
    const int o = i - 786432;           // o = tap*1024 + m
    const int tap = o >> 10, m = o & 1023;
    off = m * 9 + tap;                  // src is [m][tap]
    if (o >= 9216) return;
  }
  dst[i] = __float2bfloat16(ldd(src, off, isf));
}

// ---------------- prenorm + transpose: xhat_t[n][c], x0t[n][c] ----------------
__global__ __launch_bounds__(256) void prenorm_t_kernel(
    const int* dflag, const void* __restrict__ x0,
    const float* __restrict__ bn, bf16* __restrict__ xhat_t, bf16* __restrict__ x0t)
{
  const int isf = dflag[0];
  const int tid = blockIdx.x * 256 + threadIdx.x;   // < 262144
  const int pix = tid & 32767;                      // consecutive lanes -> consecutive pix
  const int c32 = tid >> 15;                        // 0..7 (32 channels each)
  const int b = pix >> 14, nb = pix & 16383;
  const long base = (long)b * 4194304 + nb;
  alignas(16) short ho[32];
  alignas(16) short hh[32];
  #pragma unroll
  for (int j = 0; j < 32; ++j) {
    const int c = c32 * 32 + j;
    const float xv = ldd(x0, base + (long)c * 16384, isf);
    ho[j] = f2s(xv);
    hh[j] = f2s(gelu_f(xv * bn[c] + bn[256 + c]));
  }
  const long obase = (long)pix * 256 + c32 * 32;
  #pragma unroll
  for (int q = 0; q < 4; ++q) {
    *(uint4*)(x0t + obase + q * 8)    = *(const uint4*)(ho + q * 8);
    *(uint4*)(xhat_t + obase + q * 8) = *(const uint4*)(hh + q * 8);
  }
}

// ---------------- MFMA GEMM: out[n][m] = epi( sum_k in[n][k] * w[m][k] ) ----
// in: [N][K] bf16 pixel-major; w: [M][K] bf16. grid (N/128, M/128), 256 thr.
// MODE 0 PLAIN : out bf16 = acc                       (qkv merged, M=768)
// MODE 1 MERGE : out bf16 = acc + sv[m] + res[n][m]   (merge + bias + residual)
// MODE 2 W1    : out bf16 = gelu(acc*sv[m]+tv[m])     (w1 + bn1 + gelu)
// MODE 3 OUT   : channel-major (runtime dtype) via LDS transpose:
//                out[m][n] = acc*sv[m]+tv[m] + res[n][m]  (w2 + bn3 + residual)
template <int MODE>
__global__ __launch_bounds__(256) void mfma_gemm(
    const int* dflag,
    const bf16* __restrict__ in, const bf16* __restrict__ w,
    void* __restrict__ out, long obase, const bf16* __restrict__ res,
    const float* __restrict__ sv, const float* __restrict__ tv,
    int N, int M, int K)
{
  alignas(16) __shared__ char smem[34816];   // staging 20480 B; OUT tile 34816 B
  bf16* inT = (bf16*)smem;                   // [128][40]
  bf16* wT  = (bf16*)(smem + 10240);         // [128][40]
  const int t = threadIdx.x;
  const int n0 = blockIdx.x * 128, m0 = blockIdx.y * 128;
  const int sr = t >> 1, sk = (t & 1) * 16;
  const int wid = t >> 6, lane = t & 63;
  const int nw = (wid & 1) * 64, mw = (wid >> 1) * 64;
  const int l15 = lane & 15, quad = lane >> 4;
  f32x4 acc[4][4];
  #pragma unroll
  for (int i = 0; i < 4; ++i)
    #pragma unroll
    for (int j = 0; j < 4; ++j) acc[i][j] = 0.f;
  const long inRow = (long)(n0 + sr) * K + sk;
  const long wRow = (long)(m0 + sr) * K + sk;
  for (int k0 = 0; k0 < K; k0 += 32) {
    const uint4 a0 = *(const uint4*)(in + inRow + k0);
    const uint4 a1 = *(const uint4*)(in + inRow + k0 + 8);
    const uint4 b0 = *(const uint4*)(w + wRow + k0);
    const uint4 b1 = *(const uint4*)(w + wRow + k0 + 8);
    __syncthreads();
    *(uint4*)(inT + sr * 40 + sk) = a0;
    *(uint4*)(inT + sr * 40 + sk + 8) = a1;
    *(uint4*)(wT + sr * 40 + sk) = b0;
    *(uint4*)(wT + sr * 40 + sk + 8) = b1;
    __syncthreads();
    s16x8 af[4], bfv[4];
    #pragma unroll
    for (int i = 0; i < 4; ++i)
      af[i] = *(const s16x8*)(inT + (nw + i * 16 + l15) * 40 + quad * 8);
    #pragma unroll
    for (int i = 0; i < 4; ++i)
      bfv[i] = *(const s16x8*)(wT + (mw + i * 16 + l15) * 40 + quad * 8);
    #pragma unroll
    for (int i = 0; i < 4; ++i)
      #pragma unroll
      for (int j = 0; j < 4; ++j)
        acc[i][j] = __builtin_amdgcn_mfma_f32_16x16x32_bf16(af[i], bfv[j], acc[i][j], 0, 0, 0);
  }
  if (MODE != 3) {
    bf16* ob = (bf16*)out;
    #pragma unroll
    for (int i = 0; i < 4; ++i) {
      #pragma unroll
      for (int r = 0; r < 4; ++r) {
        const int n = n0 + nw + i * 16 + quad * 4 + r;
        #pragma unroll
        for (int j = 0; j < 4; ++j) {
          const int m = m0 + mw + j * 16 + l15;
          float vv = acc[i][j][r];
          if (MODE == 1) vv += sv[m] + bf2f(res[(long)n * 256 + m]);
          if (MODE == 2) vv = gelu_f(vv * sv[m] + tv[m]);
          ob[(long)n * M + m] = __float2bfloat16(vv);
        }
      }
    }
  } else {
    const int isf = dflag[0];
    __syncthreads();                         // staging LDS now dead
    bf16* T = (bf16*)smem;                   // [128][136]
    #pragma unroll
    for (int i = 0; i < 4; ++i)
      #pragma unroll
      for (int r = 0; r < 4; ++r) {
        const int n = nw + i * 16 + quad * 4 + r;
        #pragma unroll
        for (int j = 0; j < 4; ++j) {
          const int m = mw + j * 16 + l15;
          const float vv = acc[i][j][r] * sv[m0 + m] + tv[m0 + m]
                         + bf2f(res[(long)(n0 + n) * 256 + m0 + m]);
          T[m * 136 + n] = __float2bfloat16(vv);
        }
      }
    __syncthreads();
    const int mr = t >> 1, half = (t & 1) * 64;
    if (!isf) {
      bf16* bo = (bf16*)out + obase;
      #pragma unroll
      for (int jj = 0; jj < 8; ++jj)
        *(uint4*)(bo + (long)(m0 + mr) * N + n0 + half + jj * 8) =
            *(const uint4*)(T + mr * 136 + half + jj * 8);
    } else {
      float* fo = (float*)out + obase;
      #pragma unroll
      for (int jj = 0; jj < 8; ++jj)
        #pragma unroll
        for (int e = 0; e < 8; ++e)
          fo[(long)(m0 + mr) * N + n0 + half + jj * 8 + e] =
              bf2f(T[mr * 136 + half + jj * 8 + e]);
    }
  }
}

// ---------------- window means of gelu(bn0(x0)), layout [b][c][nw] ----------
__global__ __launch_bounds__(256) void xmean_kernel(const int* dflag,
                                                    const void* __restrict__ x0,
                                                    const float* __restrict__ bn,
                                                    float* __restrict__ xm)
{
  const int isf = dflag[0];
  int tid = blockIdx.x * 256 + threadIdx.x;      // < 131072
  int n = tid & 255, c = (tid >> 8) & 255, b = tid >> 16;
  const float s0 = bn[c], t0 = bn[256 + c];
  const long base = (long)b * 4194304 + (long)c * 16384 + ((n >> 4) * 8) * 128 + (n & 15) * 8;
  float s = 0.f;
  #pragma unroll
  for (int r = 0; r < 8; ++r)
    #pragma unroll
    for (int cc = 0; cc < 8; ++cc)
      s += gelu_f(ldd(x0, base + r * 128 + cc, isf) * s0 + t0);
  xm[tid] = s * 0.015625f;
}

// ---------------- project window means through q_w/k_w (fp32) ----------------
__global__ __launch_bounds__(256) void meanproj_kernel(const int* dflag,
    const void* __restrict__ qw, const void* __restrict__ kw,
    const float* __restrict__ xm, float* __restrict__ qm, float* __restrict__ km)
{
  const int isf = dflag[0];
  int tid = blockIdx.x * 256 + threadIdx.x;      // < 131072
  int nw = tid & 255, o = (tid >> 8) & 255, b = tid >> 16;
  float sq = 0.f, sk = 0.f;
  for (int c = 0; c < 256; ++c) {
    const float x = xm[(b * 256 + c) * 256 + nw];
    sq += ldd(qw, o * 256 + c, isf) * x;
    sk += ldd(kw, o * 256 + c, isf) * x;
  }
  qm[(b * 256 + o) * 256 + nw] = sq;
  km[(b * 256 + o) * 256 + nw] = sk;
}

// ---------------- sim + top-8 (stable: ties -> lower index) ----------------
__global__ __launch_bounds__(256) void topk_kernel(const float* __restrict__ qm,
                                                   const float* __restrict__ km,
                                                   int* __restrict__ topki)
{
  const int nq = blockIdx.x, b = blockIdx.y, t = threadIdx.x;
  float sim = 0.f;
  for (int c = 0; c < 256; ++c)
    sim += qm[(b * 256 + c) * 256 + nq] * km[(b * 256 + c) * 256 + t];
  __shared__ float vals[256];
  __shared__ float rv[256];
  __shared__ int ri[256];
  vals[t] = sim;
  __syncthreads();
  for (int j = 0; j < 8; ++j) {
    rv[t] = vals[t]; ri[t] = t;
    __syncthreads();
    for (int off = 128; off > 0; off >>= 1) {
      if (t < off) {
        float v2 = rv[t + off]; int i2 = ri[t + off];
        if (v2 > rv[t] || (v2 == rv[t] && i2 < ri[t])) { rv[t] = v2; ri[t] = i2; }
      }
      __syncthreads();
    }
    const int w = ri[0];
    if (t == 0) topki[(b * 256 + nq) * 8 + j] = w;
    __syncthreads();
    if (t == w) vals[t] = -3.0e38f;
    __syncthreads();
  }
}

// ---------------- top-k window linear attention ----------------------------
// q/k/v interleaved: qkv[pix][768] = [q 0..255 | k 256..511 | v 512..767]
// Staging mapping px_l = t&15 (lane-minor) + float4 LDS writes: <=4-way banks.
__global__ __launch_bounds__(256) void attn_kernel(
    const bf16* __restrict__ qkv, const int* __restrict__ topki,
    bf16* __restrict__ msg)
{
  __shared__ float smem[13888];   // phase1: keL[16][260] | vsL[16][260]; phase2: kvs[256][36] | qeL[16][292]
  __shared__ float ksum_s[256];
  __shared__ float zs[128];
  const int n = blockIdx.x, b = blockIdx.y, t = threadIdx.x;
  const int h = t >> 5, sub = t & 31;
  const int dt = sub & 3, et = sub >> 2;         // microtile: 8 d's x 4 e's
  const long bpix = (long)b * 16384;
  float* keL = smem;
  float* vsL = smem + 4160;
  float kvacc[8][4] = {};
  float ksum_acc = 0.f;
  const int px_l = t & 15;                       // pixel-in-chunk (lane-minor!)
  const int c0 = (t >> 4) * 16;                  // 16 channels per thread
  for (int j = 0; j < 8; ++j) {
    const int wsel = topki[(b * 256 + n) * 8 + j];
    const int kh0 = (wsel >> 4) * 8, kw0 = (wsel & 15) * 8;
    for (int ch = 0; ch < 4; ++ch) {
      const int l2 = ch * 16 + px_l;
      const long gp = bpix + (kh0 + (l2 >> 3)) * 128 + kw0 + (l2 & 7);
      const bf16* kp = qkv + gp * 768 + 256 + c0;
      const s16x8 k8a = *(const s16x8*)(kp);
      const s16x8 k8b = *(const s16x8*)(kp + 8);
      const s16x8 v8a = *(const s16x8*)(kp + 256);
      const s16x8 v8b = *(const s16x8*)(kp + 264);
      float kef[16], vsf[16];
      #pragma unroll
      for (int e = 0; e < 8; ++e) {
        kef[e]     = elu1(s2f(k8a[e]));
        kef[e + 8] = elu1(s2f(k8b[e]));
        vsf[e]     = s2f(v8a[e]);
        vsf[e + 8] = s2f(v8b[e]);
      }
      __syncthreads();
      float* kd = keL + px_l * 260 + c0;
      float* vd = vsL + px_l * 260 + c0;
      #pragma unroll
      for (int g = 0; g < 4; ++g) {
        *(float4*)(kd + g * 4) = make_float4(kef[4*g], kef[4*g+1], kef[4*g+2], kef[4*g+3]);
        *(float4*)(vd + g * 4) = make_float4(vsf[4*g], vsf[4*g+1], vsf[4*g+2], vsf[4*g+3]);
      }
      __syncthreads();
      #pragma unroll
      for (int s2 = 0; s2 < 16; ++s2) {
        const float* kr = keL + s2 * 260 + h * 32 + dt * 8;
        const float4 ka  = *(const float4*)kr;
        const float4 kb2 = *(const float4*)(kr + 4);
        const float4 vv  = *(const float4*)(vsL + s2 * 260 + h * 32 + et * 4);
        ksum_acc += keL[s2 * 260 + t];
        const float av[8] = {ka.x, ka.y, ka.z, ka.w, kb2.x, kb2.y, kb2.z, kb2.w};
        const float bv[4] = {vv.x, vv.y, vv.z, vv.w};
        #pragma unroll
        for (int ii = 0; ii < 8; ++ii)
          #pragma unroll
          for (int jj = 0; jj < 4; ++jj)
            kvacc[ii][jj] += av[ii] * bv[jj];
      }
    }
  }
  ksum_s[t] = ksum_acc;
  __syncthreads();                      // phase 1 done; smem reusable
  float* kvs = smem;                    // [256][36] : [(h*32+e)*36 + d]
  float* qeL = smem + 9216;             // [16][292] skewed: offset(c) = c + (c>>5)*4
  #pragma unroll
  for (int ii = 0; ii < 8; ++ii)
    #pragma unroll
    for (int jj = 0; jj < 4; ++jj)
      kvs[(h * 32 + et * 4 + jj) * 36 + dt * 8 + ii] = kvacc[ii][jj];
  __syncthreads();
  float kvr[32];                        // thread (h,e)'s full d-column of KV
  #pragma unroll
  for (int d4 = 0; d4 < 8; ++d4) {
    const float4 kq = *(const float4*)(kvs + t * 36 + d4 * 4);
    kvr[d4 * 4 + 0] = kq.x; kvr[d4 * 4 + 1] = kq.y;
    kvr[d4 * 4 + 2] = kq.z; kvr[d4 * 4 + 3] = kq.w;
  }
  const int qh0 = (n >> 4) * 8, qw0 = (n & 15) * 8;
  const int skew = (c0 >> 5) << 2;      // constant per thread (c0..c0+15 same >>5)
  for (int lg = 0; lg < 4; ++lg) {
    const int l = lg * 16 + px_l;
    const long gp = bpix + (qh0 + (l >> 3)) * 128 + qw0 + (l & 7);
    const bf16* qp = qkv + gp * 768 + c0;
    const s16x8 q8a = *(const s16x8*)(qp);
    const s16x8 q8b = *(const s16x8*)(qp + 8);
    float qef[16];
    #pragma unroll
    for (int e = 0; e < 8; ++e) {
      qef[e]     = elu1(s2f(q8a[e]));
      qef[e + 8] = elu1(s2f(q8b[e]));
    }
    __syncthreads();
    float* qd = qeL + px_l * 292 + c0 + skew;
    #pragma unroll
    for (int g = 0; g < 4; ++g)
      *(float4*)(qd + g * 4) = make_float4(qef[4*g], qef[4*g+1], qef[4*g+2], qef[4*g+3]);
    __syncthreads();
    if (t < 128) {
      const int lloc = t >> 3, hh = t & 7;
      float dot = 0.f;
      #pragma unroll
      for (int d = 0; d < 32; ++d)
        dot += qeL[lloc * 292 + hh * 36 + d] * ksum_s[hh * 32 + d];
      zs[lloc * 8 + hh] = 1.f / (dot + 1e-6f);
    }
    __syncthreads();
    #pragma unroll
    for (int ll = 0; ll < 16; ++ll) {
      const float* qr = qeL + ll * 292 + h * 36;
      float dot = 0.f;
      #pragma unroll
      for (int d4 = 0; d4 < 8; ++d4) {
        const float4 qq = *(const float4*)(qr + d4 * 4);
        dot += qq.x * kvr[d4 * 4] + qq.y * kvr[d4 * 4 + 1]
             + qq.z * kvr[d4 * 4 + 2] + qq.w * kvr[d4 * 4 + 3];
      }
      const int lo = lg * 16 + ll;
      const long opix = bpix + (qh0 + (lo >> 3)) * 128 + qw0 + (lo & 7);
      msg[opix * 256 + t] = __float2bfloat16(dot * zs[ll * 8 + h]);
    }
  }
}

// ---------------- depthwise 3x3 + bn2 + gelu (pixel-major, one batch) -------
__global__ __launch_bounds__(256) void dwconv_kernel(const bf16* __restrict__ y1,
                                                     const bf16* __restrict__ wdw,
                                                     const float* __restrict__ s2,
                                                     const float* __restrict__ t2,
                                                     bf16* __restrict__ y2)
{
  const int pix = blockIdx.x;                 // 0..16383
  const int m0 = threadIdx.x * 4;             // 0..1020
  const int x = pix & 127, yy = pix >> 7;
  float a0 = 0.f, a1 = 0.f, a2 = 0.f, a3 = 0.f;
  #pragma unroll
  for (int ky = 0; ky < 3; ++ky) {
    const int h2 = yy + ky - 1;
    if ((unsigned)h2 < 128u) {
      #pragma unroll
      for (int kx = 0; kx < 3; ++kx) {
        const int w2 = x + kx - 1;
        if ((unsigned)w2 < 128u) {
          const int tap = ky * 3 + kx;
          const s16x4 yv = *(const s16x4*)(y1 + (long)(h2 * 128 + w2) * 1024 + m0);
          const s16x4 wv = *(const s16x4*)(wdw + tap * 1024 + m0);
          a0 += s2f(yv[0]) * s2f(wv[0]);
          a1 += s2f(yv[1]) * s2f(wv[1]);
          a2 += s2f(yv[2]) * s2f(wv[2]);
          a3 += s2f(yv[3]) * s2f(wv[3]);
        }
      }
    }
  }
  const float4 sv = *(const float4*)(s2 + m0);
  const float4 tv = *(const float4*)(t2 + m0);
  s16x4 o;
  o[0] = f2s(gelu_f(a0 * sv.x + tv.x));
  o[1] = f2s(gelu_f(a1 * sv.y + tv.y));
  o[2] = f2s(gelu_f(a2 * sv.z + tv.z));
  o[3] = f2s(gelu_f(a3 * sv.w + tv.w));
  *(s16x4*)(y2 + (long)pix * 1024 + m0) = o;
}

extern "C" void kernel_launch(void* const* d_in, const int* in_sizes, int n_in,
                              void* d_out, int out_size, void* d_ws, size_t ws_size,
                              hipStream_t stream) {
  (void)in_sizes; (void)n_in; (void)out_size; (void)ws_size;
  // ---- workspace layout (bytes), peak ~104 MB, lifetimes audited ----
  // [0        , 16777216 ) xhat_t (prenorm->qkv)  | xres (merge->end)
  // [16777216 , 33554432 ) x0t    (prenorm->merge)
  // [33554432 , 83886080 ) qkv interleaved [32768][768] (qkv->attn)
  //                        | y1 [33.5,67.1) (w1->dwconv), y2 [67.1,100.7) per batch
  // [83886080 , 100663296) msg (attn->merge); dead before y2 written
  // [100663296, ...      ) wb bf16 | bnbuf | xmean | qm | km | topki | dflag
  char* W = (char*)d_ws;
  bf16*  xhat_t = (bf16*)(W);
  bf16*  xres   = (bf16*)(W);
  bf16*  x0t    = (bf16*)(W + 16777216);
  bf16*  qkv    = (bf16*)(W + 33554432);      // 50,331,648 B
  bf16*  msg    = (bf16*)(W + 83886080);
  bf16*  y1     = (bf16*)(W + 33554432);      // 33,554,432 B (one batch)
  bf16*  y2     = (bf16*)(W + 67108864);      // 33,554,432 B
  char*  S      = W + 100663296;
  bf16*  wb     = (bf16*)(S);             // 795648 elems; rows 0..767 = [768][256] qkv W
  bf16*  wmb    = wb + 196608;
  bf16*  w1b    = wb + 262144;
  bf16*  w2b    = wb + 524288;
  bf16*  wdwb   = wb + 786432;
  float* bnbuf  = (float*)(S + 1591296);  // 5376 floats
  float* xmean  = (float*)(S + 1612800);
  float* qm     = (float*)(S + 2137088);
  float* km     = (float*)(S + 2661376);
  int*   topki  = (int*)(S + 3185664);
  int*   dflag  = (int*)(S + 3202048);

  detect_kernel<<<1, 64, 0, stream>>>(d_in[0], dflag);

  bnprep_kernel<<<1, 256, 0, stream>>>(dflag,
      d_in[1], d_in[2], d_in[3], d_in[4],
      d_in[11], d_in[12], d_in[13], d_in[14],
      d_in[16], d_in[17], d_in[18], d_in[19],
      d_in[21], d_in[22], d_in[23], d_in[24],
      d_in[9], bnbuf);
  wconv_kernel<<<3108, 256, 0, stream>>>(dflag,
      d_in[5], d_in[6], d_in[7], d_in[8], d_in[10], d_in[20], d_in[15], wb);
  prenorm_t_kernel<<<1024, 256, 0, stream>>>(dflag, d_in[0], bnbuf, xhat_t, x0t);
  xmean_kernel<<<512, 256, 0, stream>>>(dflag, d_in[0], bnbuf, xmean);
  meanproj_kernel<<<512, 256, 0, stream>>>(dflag, d_in[5], d_in[6], xmean, qm, km);

  // merged qkv GEMM: [32768][256] x [768][256]^T -> qkv[32768][768]
  mfma_gemm<0><<<dim3(256, 6), 256, 0, stream>>>(dflag,
      xhat_t, wb, (void*)qkv, 0, nullptr, nullptr, nullptr, 32768, 768, 256);

  topk_kernel<<<dim3(256, 2), 256, 0, stream>>>(qm, km, topki);
  attn_kernel<<<dim3(256, 2), 256, 0, stream>>>(qkv, topki, msg);

  // merge + bias + residual: xres[n][c] (overwrites dead xhat_t)
  mfma_gemm<1><<<dim3(256, 2), 256, 0, stream>>>(dflag,
      msg, wmb, (void*)xres, 0, x0t, bnbuf + 5120, nullptr, 32768, 256, 256);

  // MLP tail per batch
  for (int b = 0; b < 2; ++b) {
    bf16* xres_b = xres + (long)b * 4194304;
    mfma_gemm<2><<<dim3(128, 8), 256, 0, stream>>>(dflag,
        xres_b, w1b, (void*)y1, 0, nullptr, bnbuf + 512, bnbuf + 1536, 16384, 1024, 256);
    dwconv_kernel<<<16384, 256, 0, stream>>>(y1, wdwb, bnbuf + 2560, bnbuf + 3584, y2);
    mfma_gemm<3><<<dim3(128, 2), 256, 0, stream>>>(dflag,
        y2, w2b, d_out, (long)b * 4194304, xres_b,
        bnbuf + 4608, bnbuf + 4864, 16384, 256, 1024);
  }
}

// Round 7
// 580.545 us; speedup vs baseline: 1.3144x; 1.3144x over previous
//
#include <hip/hip_runtime.h>
#include <hip/hip_bf16.h>
#include <type_traits>

typedef __hip_bfloat16 bf16;
typedef __attribute__((ext_vector_type(8))) short s16x8;
typedef __attribute__((ext_vector_type(4))) short s16x4;
typedef __attribute__((ext_vector_type(4))) float f32x4;

#define DEVI __device__ __forceinline__

DEVI float bf2f(bf16 x) { return __bfloat162float(x); }
DEVI float to_f(float x) { return x; }
DEVI float to_f(bf16 x) { return __bfloat162float(x); }
DEVI float gelu_f(float x) { return 0.5f * x * (1.0f + erff(x * 0.7071067811865476f)); }
DEVI float elu1(float x) { return x > 0.f ? x + 1.f : __expf(x); }  // elu(x)+1
DEVI float s2f(short s) {
  unsigned u = ((unsigned)(unsigned short)s) << 16;
  float f; __builtin_memcpy(&f, &u, 4); return f;
}
DEVI short f2s(float x) {
  bf16 h = __float2bfloat16(x);
  short s; __builtin_memcpy(&s, &h, 2); return s;
}

// ---------------- dtype detector ----------------
__global__ void detect_kernel(const void* x0, int* dflag) {
  const int t = threadIdx.x;                  // 64 threads
  const bf16* p = (const bf16*)x0;
  float v = bf2f(p[t * 2]);
  bool ok = (fabsf(v) <= 64.0f);              // false for NaN too
  unsigned long long m = __ballot(ok);
  if (t == 0) dflag[0] = (m == ~0ull) ? 0 : 1;   // 0 = bf16, 1 = fp32
}

// ---------------- bn scale/shift + merge-bias precompute ----------------
// layout: s0[256] t0[256] s1[1024] t1[1024] s2[1024] t2[1024] s3[256] t3[256] mbias[256]
template <typename TIN>
__global__ __launch_bounds__(256) void bnprep_kernel(
    const int* dflag, int want,
    const TIN* g0, const TIN* b0, const TIN* m0, const TIN* v0,
    const TIN* g1, const TIN* b1, const TIN* m1, const TIN* v1,
    const TIN* g2, const TIN* b2, const TIN* m2, const TIN* v2,
    const TIN* g3, const TIN* b3, const TIN* m3, const TIN* v3,
    const TIN* mb, float* out)
{
  if (dflag[0] != want) return;
  int t = threadIdx.x;
  {
    float s = to_f(g0[t]) / sqrtf(to_f(v0[t]) + 1e-5f);
    out[t] = s; out[256 + t] = to_f(b0[t]) - to_f(m0[t]) * s;
  }
  for (int i = t; i < 1024; i += 256) {
    float s = to_f(g1[i]) / sqrtf(to_f(v1[i]) + 1e-5f);
    out[512 + i] = s; out[1536 + i] = to_f(b1[i]) - to_f(m1[i]) * s;
  }
  for (int i = t; i < 1024; i += 256) {
    float s = to_f(g2[i]) / sqrtf(to_f(v2[i]) + 1e-5f);
    out[2560 + i] = s; out[3584 + i] = to_f(b2[i]) - to_f(m2[i]) * s;
  }
  {
    float s = to_f(g3[t]) / sqrtf(to_f(v3[t]) + 1e-5f);
    out[4608 + t] = s; out[4864 + t] = to_f(b3[t]) - to_f(m3[t]) * s;
    out[5120 + t] = to_f(mb[t]);
  }
}

// ---------------- weight convert to bf16 (concatenated dst) ----------------
// dst elems: [0,65536) qw | kw | vw | mw ... [262144,524288) w1 |
// [524288,786432) w2 | [786432,795648) wdw as [tap][1024] (tap-major!)
// Rows 0..767 of dst form the concatenated [768][256] qkv weight.
template <typename TIN>
__global__ __launch_bounds__(256) void wconv_kernel(
    const int* dflag, int want,
    const TIN* qw, const TIN* kw, const TIN* vw, const TIN* mw,
    const TIN* w1, const TIN* w2, const TIN* dw, bf16* dst)
{
  if (dflag[0] != want) return;
  int i = blockIdx.x * 256 + threadIdx.x;
  if (i >= 795648) return;
  const TIN* src; int off;
  if (i < 262144) {
    src = (i < 65536) ? qw : (i < 131072) ? kw : (i < 196608) ? vw : mw;
    off = i & 65535;
  } else if (i < 524288) { src = w1; off = i - 262144; }
  else if (i < 786432) { src = w2; off = i - 524288; }
  else {
    src = dw;
    const int o = i - 786432;           // o = tap*1024 + m
    const int tap = o >> 10, m = o & 1023;
    off = m * 9 + tap;                  // src is [m][tap]
    if (o >= 9216) return;
  }
  dst[i] = __float2bfloat16(to_f(src[off]));
}

// ---------------- prenorm + transpose: xhat_t[n][c], x0t[n][c] ----------------
template <typename TIN>
__global__ __launch_bounds__(256) void prenorm_t_kernel(
    const int* dflag, int want, const TIN* __restrict__ x0,
    const float* __restrict__ bn, bf16* __restrict__ xhat_t, bf16* __restrict__ x0t)
{
  if (dflag[0] != want) return;
  const int tid = blockIdx.x * 256 + threadIdx.x;   // < 262144
  const int pix = tid & 32767;                      // consecutive lanes -> consecutive pix
  const int c32 = tid >> 15;                        // 0..7 (32 channels each)
  const int b = pix >> 14, nb = pix & 16383;
  const TIN* xp = x0 + (long)b * 4194304 + nb;
  alignas(16) short ho[32];
  alignas(16) short hh[32];
  #pragma unroll
  for (int j = 0; j < 32; ++j) {
    const int c = c32 * 32 + j;
    const float xv = to_f(xp[(long)c * 16384]);
    ho[j] = f2s(xv);
    hh[j] = f2s(gelu_f(xv * bn[c] + bn[256 + c]));
  }
  const long obase = (long)pix * 256 + c32 * 32;
  #pragma unroll
  for (int q = 0; q < 4; ++q) {
    *(uint4*)(x0t + obase + q * 8)    = *(const uint4*)(ho + q * 8);
    *(uint4*)(xhat_t + obase + q * 8) = *(const uint4*)(hh + q * 8);
  }
}

// ---------------- MFMA GEMM: out[n][m] = epi( sum_k in[n][k] * w[m][k] ) ----
// MODE 0 PLAIN : out bf16 = acc                       (qkv merged, M=768)
// MODE 1 MERGE : out bf16 = acc + sv[m] + res[n][m]   (merge + bias + residual)
// MODE 2 W1    : out bf16 = gelu(acc*sv[m]+tv[m])     (w1 + bn1 + gelu)
// MODE 3 OUT   : channel-major (runtime dtype) via LDS transpose:
//                out[m][n] = acc*sv[m]+tv[m] + res[n][m]  (w2 + bn3 + residual)
template <int MODE>
__global__ __launch_bounds__(256) void mfma_gemm(
    const int* dflag,
    const bf16* __restrict__ in, const bf16* __restrict__ w,
    void* __restrict__ out, long obase, const bf16* __restrict__ res,
    const float* __restrict__ sv, const float* __restrict__ tv,
    int N, int M, int K)
{
  alignas(16) __shared__ char smem[34816];   // staging 20480 B; OUT tile 34816 B
  bf16* inT = (bf16*)smem;                   // [128][40]
  bf16* wT  = (bf16*)(smem + 10240);         // [128][40]
  const int t = threadIdx.x;
  const int n0 = blockIdx.x * 128, m0 = blockIdx.y * 128;
  const int sr = t >> 1, sk = (t & 1) * 16;
  const int wid = t >> 6, lane = t & 63;
  const int nw = (wid & 1) * 64, mw = (wid >> 1) * 64;
  const int l15 = lane & 15, quad = lane >> 4;
  f32x4 acc[4][4];
  #pragma unroll
  for (int i = 0; i < 4; ++i)
    #pragma unroll
    for (int j = 0; j < 4; ++j) acc[i][j] = 0.f;
  const long inRow = (long)(n0 + sr) * K + sk;
  const long wRow = (long)(m0 + sr) * K + sk;
  for (int k0 = 0; k0 < K; k0 += 32) {
    const uint4 a0 = *(const uint4*)(in + inRow + k0);
    const uint4 a1 = *(const uint4*)(in + inRow + k0 + 8);
    const uint4 b0 = *(const uint4*)(w + wRow + k0);
    const uint4 b1 = *(const uint4*)(w + wRow + k0 + 8);
    __syncthreads();
    *(uint4*)(inT + sr * 40 + sk) = a0;
    *(uint4*)(inT + sr * 40 + sk + 8) = a1;
    *(uint4*)(wT + sr * 40 + sk) = b0;
    *(uint4*)(wT + sr * 40 + sk + 8) = b1;
    __syncthreads();
    s16x8 af[4], bfv[4];
    #pragma unroll
    for (int i = 0; i < 4; ++i)
      af[i] = *(const s16x8*)(inT + (nw + i * 16 + l15) * 40 + quad * 8);
    #pragma unroll
    for (int i = 0; i < 4; ++i)
      bfv[i] = *(const s16x8*)(wT + (mw + i * 16 + l15) * 40 + quad * 8);
    #pragma unroll
    for (int i = 0; i < 4; ++i)
      #pragma unroll
      for (int j = 0; j < 4; ++j)
        acc[i][j] = __builtin_amdgcn_mfma_f32_16x16x32_bf16(af[i], bfv[j], acc[i][j], 0, 0, 0);
  }
  if (MODE != 3) {
    bf16* ob = (bf16*)out;
    #pragma unroll
    for (int i = 0; i < 4; ++i) {
      #pragma unroll
      for (int r = 0; r < 4; ++r) {
        const int n = n0 + nw + i * 16 + quad * 4 + r;
        #pragma unroll
        for (int j = 0; j < 4; ++j) {
          const int m = m0 + mw + j * 16 + l15;
          float vv = acc[i][j][r];
          if (MODE == 1) vv += sv[m] + bf2f(res[(long)n * 256 + m]);
          if (MODE == 2) vv = gelu_f(vv * sv[m] + tv[m]);
          ob[(long)n * M + m] = __float2bfloat16(vv);
        }
      }
    }
  } else {
    const int isf = dflag[0];
    __syncthreads();                         // staging LDS now dead
    bf16* T = (bf16*)smem;                   // [128][136]
    #pragma unroll
    for (int i = 0; i < 4; ++i)
      #pragma unroll
      for (int r = 0; r < 4; ++r) {
        const int n = nw + i * 16 + quad * 4 + r;
        #pragma unroll
        for (int j = 0; j < 4; ++j) {
          const int m = mw + j * 16 + l15;
          const float vv = acc[i][j][r] * sv[m0 + m] + tv[m0 + m]
                         + bf2f(res[(long)(n0 + n) * 256 + m0 + m]);
          T[m * 136 + n] = __float2bfloat16(vv);
        }
      }
    __syncthreads();
    const int mr = t >> 1, half = (t & 1) * 64;
    if (!isf) {
      bf16* bo = (bf16*)out + obase;
      #pragma unroll
      for (int jj = 0; jj < 8; ++jj)
        *(uint4*)(bo + (long)(m0 + mr) * N + n0 + half + jj * 8) =
            *(const uint4*)(T + mr * 136 + half + jj * 8);
    } else {
      float* fo = (float*)out + obase;
      #pragma unroll
      for (int jj = 0; jj < 8; ++jj)
        #pragma unroll
        for (int e = 0; e < 8; ++e)
          fo[(long)(m0 + mr) * N + n0 + half + jj * 8 + e] =
              bf2f(T[mr * 136 + half + jj * 8 + e]);
    }
  }
}

// ---------------- window means of gelu(bn0(x0)), layout [b][c][nw] ----------
template <typename TIN>
__global__ __launch_bounds__(256) void xmean_kernel(const int* dflag, int want,
                                                    const TIN* __restrict__ x0,
                                                    const float* __restrict__ bn,
                                                    float* __restrict__ xm)
{
  if (dflag[0] != want) return;
  int tid = blockIdx.x * 256 + threadIdx.x;      // < 131072
  int n = tid & 255, c = (tid >> 8) & 255, b = tid >> 16;
  const float s0 = bn[c], t0 = bn[256 + c];
  const long base = (long)b * 4194304 + (long)c * 16384 + ((n >> 4) * 8) * 128 + (n & 15) * 8;
  float s = 0.f;
  #pragma unroll
  for (int r = 0; r < 8; ++r)
    #pragma unroll
    for (int cc = 0; cc < 8; ++cc)
      s += gelu_f(to_f(x0[base + r * 128 + cc]) * s0 + t0);
  xm[tid] = s * 0.015625f;
}

// ---------------- project window means through q_w/k_w (fp32) ----------------
template <typename TIN>
__global__ __launch_bounds__(256) void meanproj_kernel(const int* dflag, int want,
    const TIN* __restrict__ qw, const TIN* __restrict__ kw,
    const float* __restrict__ xm, float* __restrict__ qm, float* __restrict__ km)
{
  if (dflag[0] != want) return;
  int tid = blockIdx.x * 256 + threadIdx.x;      // < 131072
  int nw = tid & 255, o = (tid >> 8) & 255, b = tid >> 16;
  float sq = 0.f, sk = 0.f;
  for (int c = 0; c < 256; ++c) {
    const float x = xm[(b * 256 + c) * 256 + nw];
    sq += to_f(qw[o * 256 + c]) * x;
    sk += to_f(kw[o * 256 + c]) * x;
  }
  qm[(b * 256 + o) * 256 + nw] = sq;
  km[(b * 256 + o) * 256 + nw] = sk;
}

// ---------------- sim + top-8 (stable: ties -> lower index) ----------------
__global__ __launch_bounds__(256) void topk_kernel(const float* __restrict__ qm,
                                                   const float* __restrict__ km,
                                                   int* __restrict__ topki)
{
  const int nq = blockIdx.x, b = blockIdx.y, t = threadIdx.x;
  float sim = 0.f;
  for (int c = 0; c < 256; ++c)
    sim += qm[(b * 256 + c) * 256 + nq] * km[(b * 256 + c) * 256 + t];
  __shared__ float vals[256];
  __shared__ float rv[256];
  __shared__ int ri[256];
  vals[t] = sim;
  __syncthreads();
  for (int j = 0; j < 8; ++j) {
    rv[t] = vals[t]; ri[t] = t;
    __syncthreads();
    for (int off = 128; off > 0; off >>= 1) {
      if (t < off) {
        float v2 = rv[t + off]; int i2 = ri[t + off];
        if (v2 > rv[t] || (v2 == rv[t] && i2 < ri[t])) { rv[t] = v2; ri[t] = i2; }
      }
      __syncthreads();
    }
    const int w = ri[0];
    if (t == 0) topki[(b * 256 + nq) * 8 + j] = w;
    __syncthreads();
    if (t == w) vals[t] = -3.0e38f;
    __syncthreads();
  }
}

// ---------------- top-k window linear attention: MFMA phase-1 ---------------
// qkv[pix][768] = [q|k|v]. Phase 1: KV[d][v] per head via mfma_16x16x32_bf16
// over 16 chunks of 32 gathered pixels; ksum folded into staging.
// Phase 2 (Q·KV, Z) identical to the verified scalar version.
__global__ __launch_bounds__(256) void attn_kernel(
    const bf16* __restrict__ qkv, const int* __restrict__ topki,
    bf16* __restrict__ msg)
{
  alignas(16) __shared__ char smem_raw[57344];
  __shared__ float ksum_s[256];
  __shared__ float zs[128];
  bf16* keB = (bf16*)smem_raw;                  // phase1 [256][40] bf16 (elu'd K)
  bf16* vsB = (bf16*)(smem_raw + 20480);        // phase1 [256][40] bf16 (V)
  float* red = (float*)(smem_raw + 40960);      // phase1 [256][16] ksum partials
  float* kvs = (float*)smem_raw;                // phase2 [256][36] f32
  float* qeL = (float*)(smem_raw + 36864);      // phase2 [16][292] f32 skewed
  const int n = blockIdx.x, b = blockIdx.y, t = threadIdx.x;
  const long bpix = (long)b * 16384;
  const int lane = t & 63, wid = t >> 6;
  const int l15 = lane & 15, quad = lane >> 4;
  const int spx = (t & 15) * 2;        // staging: even pixel slot (0..30)
  const int scg = t >> 4;              // staging: channel group (16 ch each)
  f32x4 kvacc[2][2][2];                // [head-sub][dtile][vtile]
  #pragma unroll
  for (int a = 0; a < 2; ++a)
    #pragma unroll
    for (int c = 0; c < 2; ++c)
      #pragma unroll
      for (int d = 0; d < 2; ++d) kvacc[a][c][d] = 0.f;
  float ksp[16];
  #pragma unroll
  for (int j = 0; j < 16; ++j) ksp[j] = 0.f;

  for (int ck = 0; ck < 16; ++ck) {    // 16 chunks x 32 px = 512 gathered px
    const int jw = ck >> 1;
    const int wsel = topki[(b * 256 + n) * 8 + jw];
    const int kh0 = (wsel >> 4) * 8, kw0 = (wsel & 15) * 8;
    const int l2a = (ck & 1) * 32 + spx;
    const long gpa = bpix + (kh0 + (l2a >> 3)) * 128 + kw0 + (l2a & 7);
    const long gpb = bpix + (kh0 + ((l2a + 1) >> 3)) * 128 + kw0 + ((l2a + 1) & 7);
    const bf16* pa = qkv + gpa * 768 + 256 + scg * 16;
    const bf16* pb = qkv + gpb * 768 + 256 + scg * 16;
    alignas(16) short ka[16], kb[16], va[16], vb[16];
    *(s16x8*)(ka)     = *(const s16x8*)(pa);
    *(s16x8*)(ka + 8) = *(const s16x8*)(pa + 8);
    *(s16x8*)(kb)     = *(const s16x8*)(pb);
    *(s16x8*)(kb + 8) = *(const s16x8*)(pb + 8);
    *(s16x8*)(va)     = *(const s16x8*)(pa + 256);
    *(s16x8*)(va + 8) = *(const s16x8*)(pa + 264);
    *(s16x8*)(vb)     = *(const s16x8*)(pb + 256);
    *(s16x8*)(vb + 8) = *(const s16x8*)(pb + 264);
    __syncthreads();                   // prev chunk's fragment reads done
    #pragma unroll
    for (int j = 0; j < 16; ++j) {
      const float e0 = elu1(s2f(ka[j])), e1 = elu1(s2f(kb[j]));
      ksp[j] += e0 + e1;
      const unsigned kp = (unsigned)(unsigned short)f2s(e0)
                        | ((unsigned)(unsigned short)f2s(e1) << 16);
      *(unsigned*)(keB + (scg * 16 + j) * 40 + spx) = kp;
      const unsigned vp = (unsigned)(unsigned short)va[j]
                        | ((unsigned)(unsigned short)vb[j] << 16);
      *(unsigned*)(vsB + (scg * 16 + j) * 40 + spx) = vp;
    }
    __syncthreads();
    #pragma unroll
    for (int hs = 0; hs < 2; ++hs) {   // wave wid handles heads 2*wid, 2*wid+1
      const int cb = (wid * 2 + hs) * 32;
      const s16x8 a0 = *(const s16x8*)(keB + (cb + l15) * 40 + quad * 8);
      const s16x8 a1 = *(const s16x8*)(keB + (cb + 16 + l15) * 40 + quad * 8);
      const s16x8 b0 = *(const s16x8*)(vsB + (cb + l15) * 40 + quad * 8);
      const s16x8 b1 = *(const s16x8*)(vsB + (cb + 16 + l15) * 40 + quad * 8);
      kvacc[hs][0][0] = __builtin_amdgcn_mfma_f32_16x16x32_bf16(a0, b0, kvacc[hs][0][0], 0, 0, 0);
      kvacc[hs][0][1] = __builtin_amdgcn_mfma_f32_16x16x32_bf16(a0, b1, kvacc[hs][0][1], 0, 0, 0);
      kvacc[hs][1][0] = __builtin_amdgcn_mfma_f32_16x16x32_bf16(a1, b0, kvacc[hs][1][0], 0, 0, 0);
      kvacc[hs][1][1] = __builtin_amdgcn_mfma_f32_16x16x32_bf16(a1, b1, kvacc[hs][1][1], 0, 0, 0);
    }
  }
  // ksum reduction: channel c's 16 partial-holders are threads (c>>4)*16+p
  __syncthreads();
  #pragma unroll
  for (int j = 0; j < 16; ++j) red[t * 16 + j] = ksp[j];
  __syncthreads();
  {
    float ks = 0.f;
    const int cg = t >> 4, cj = t & 15;
    #pragma unroll
    for (int p = 0; p < 16; ++p) ks += red[(cg * 16 + p) * 16 + cj];
    ksum_s[t] = ks;
  }
  __syncthreads();                     // red reads done; kvs may overwrite
  #pragma unroll
  for (int hs = 0; hs < 2; ++hs)
    #pragma unroll
    for (int dt = 0; dt < 2; ++dt)
      #pragma unroll
      for (int vt = 0; vt < 2; ++vt)
        #pragma unroll
        for (int r = 0; r < 4; ++r)
          kvs[((wid * 2 + hs) * 32 + vt * 16 + l15) * 36 + dt * 16 + quad * 4 + r] =
              kvacc[hs][dt][vt][r];
  __syncthreads();
  // -------- phase 2 (unchanged, verified) --------
  const int h = t >> 5;
  const int px_l = t & 15;
  const int c0 = (t >> 4) * 16;
  float kvr[32];
  #pragma unroll
  for (int d4 = 0; d4 < 8; ++d4) {
    const float4 kq = *(const float4*)(kvs + t * 36 + d4 * 4);
    kvr[d4 * 4 + 0] = kq.x; kvr[d4 * 4 + 1] = kq.y;
    kvr[d4 * 4 + 2] = kq.z; kvr[d4 * 4 + 3] = kq.w;
  }
  const int qh0 = (n >> 4) * 8, qw0 = (n & 15) * 8;
  const int skew = (c0 >> 5) << 2;
  for (int lg = 0; lg < 4; ++lg) {
    const int l = lg * 16 + px_l;
    const long gp = bpix + (qh0 + (l >> 3)) * 128 + qw0 + (l & 7);
    const bf16* qp = qkv + gp * 768 + c0;
    const s16x8 q8a = *(const s16x8*)(qp);
    const s16x8 q8b = *(const s16x8*)(qp + 8);
    float qef[16];
    #pragma unroll
    for (int e = 0; e < 8; ++e) {
      qef[e]     = elu1(s2f(q8a[e]));
      qef[e + 8] = elu1(s2f(q8b[e]));
    }
    __syncthreads();
    float* qd = qeL + px_l * 292 + c0 + skew;
    #pragma unroll
    for (int g = 0; g < 4; ++g)
      *(float4*)(qd + g * 4) = make_float4(qef[4*g], qef[4*g+1], qef[4*g+2], qef[4*g+3]);
    __syncthreads();
    if (t < 128) {
      const int lloc = t >> 3, hh = t & 7;
      float dot = 0.f;
      #pragma unroll
      for (int d = 0; d < 32; ++d)
        dot += qeL[lloc * 292 + hh * 36 + d] * ksum_s[hh * 32 + d];
      zs[lloc * 8 + hh] = 1.f / (dot + 1e-6f);
    }
    __syncthreads();
    #pragma unroll
    for (int ll = 0; ll < 16; ++ll) {
      const float* qr = qeL + ll * 292 + h * 36;
      float dot = 0.f;
      #pragma unroll
      for (int d4 = 0; d4 < 8; ++d4) {
        const float4 qq = *(const float4*)(qr + d4 * 4);
        dot += qq.x * kvr[d4 * 4] + qq.y * kvr[d4 * 4 + 1]
             + qq.z * kvr[d4 * 4 + 2] + qq.w * kvr[d4 * 4 + 3];
      }
      const int lo = lg * 16 + ll;
      const long opix = bpix + (qh0 + (lo >> 3)) * 128 + qw0 + (lo & 7);
      msg[opix * 256 + t] = __float2bfloat16(dot * zs[ll * 8 + h]);
    }
  }
}

// ---------------- depthwise 3x3 + bn2 + gelu (pixel-major, one batch) -------
__global__ __launch_bounds__(256) void dwconv_kernel(const bf16* __restrict__ y1,
                                                     const bf16* __restrict__ wdw,
                                                     const float* __restrict__ s2,
                                                     const float* __restrict__ t2,
                                                     bf16* __restrict__ y2)
{
  const int pix = blockIdx.x;                 // 0..16383
  const int m0 = threadIdx.x * 4;             // 0..1020
  const int x = pix & 127, yy = pix >> 7;
  float a0 = 0.f, a1 = 0.f, a2 = 0.f, a3 = 0.f;
  #pragma unroll
  for (int ky = 0; ky < 3; ++ky) {
    const int h2 = yy + ky - 1;
    if ((unsigned)h2 < 128u) {
      #pragma unroll
      for (int kx = 0; kx < 3; ++kx) {
        const int w2 = x + kx - 1;
        if ((unsigned)w2 < 128u) {
          const int tap = ky * 3 + kx;
          const s16x4 yv = *(const s16x4*)(y1 + (long)(h2 * 128 + w2) * 1024 + m0);
          const s16x4 wv = *(const s16x4*)(wdw + tap * 1024 + m0);
          a0 += s2f(yv[0]) * s2f(wv[0]);
          a1 += s2f(yv[1]) * s2f(wv[1]);
          a2 += s2f(yv[2]) * s2f(wv[2]);
          a3 += s2f(yv[3]) * s2f(wv[3]);
        }
      }
    }
  }
  const float4 sv = *(const float4*)(s2 + m0);
  const float4 tv = *(const float4*)(t2 + m0);
  s16x4 o;
  o[0] = f2s(gelu_f(a0 * sv.x + tv.x));
  o[1] = f2s(gelu_f(a1 * sv.y + tv.y));
  o[2] = f2s(gelu_f(a2 * sv.z + tv.z));
  o[3] = f2s(gelu_f(a3 * sv.w + tv.w));
  *(s16x4*)(y2 + (long)pix * 1024 + m0) = o;
}

// ---------------- per-dtype launch stages ----------------
template <typename TIN>
static void stage_dtype_pre(int want, void* const* d_in, hipStream_t stream,
                            const int* dflag, bf16* wb, float* bnbuf,
                            bf16* xhat_t, bf16* x0t, float* xmean, float* qm, float* km)
{
  bnprep_kernel<TIN><<<1, 256, 0, stream>>>(dflag, want,
      (const TIN*)d_in[1],  (const TIN*)d_in[2],  (const TIN*)d_in[3],  (const TIN*)d_in[4],
      (const TIN*)d_in[11], (const TIN*)d_in[12], (const TIN*)d_in[13], (const TIN*)d_in[14],
      (const TIN*)d_in[16], (const TIN*)d_in[17], (const TIN*)d_in[18], (const TIN*)d_in[19],
      (const TIN*)d_in[21], (const TIN*)d_in[22], (const TIN*)d_in[23], (const TIN*)d_in[24],
      (const TIN*)d_in[9], bnbuf);
  wconv_kernel<TIN><<<3108, 256, 0, stream>>>(dflag, want,
      (const TIN*)d_in[5], (const TIN*)d_in[6], (const TIN*)d_in[7], (const TIN*)d_in[8],
      (const TIN*)d_in[10], (const TIN*)d_in[20], (const TIN*)d_in[15], wb);
  prenorm_t_kernel<TIN><<<1024, 256, 0, stream>>>(dflag, want,
      (const TIN*)d_in[0], bnbuf, xhat_t, x0t);
  xmean_kernel<TIN><<<512, 256, 0, stream>>>(dflag, want, (const TIN*)d_in[0], bnbuf, xmean);
  meanproj_kernel<TIN><<<512, 256, 0, stream>>>(dflag, want,
      (const TIN*)d_in[5], (const TIN*)d_in[6], xmean, qm, km);
}

extern "C" void kernel_launch(void* const* d_in, const int* in_sizes, int n_in,
                              void* d_out, int out_size, void* d_ws, size_t ws_size,
                              hipStream_t stream) {
  (void)in_sizes; (void)n_in; (void)out_size; (void)ws_size;
  // ---- workspace layout (bytes), peak ~104 MB, lifetimes audited ----
  // [0        , 16777216 ) xhat_t (prenorm->qkv)  | xres (merge->end)
  // [16777216 , 33554432 ) x0t    (prenorm->merge)
  // [33554432 , 83886080 ) qkv interleaved [32768][768] (qkv->attn)
  //                        | y1 [33.5,67.1), y2 [67.1,100.7) per batch
  // [83886080 , 100663296) msg (attn->merge); dead before y2 written
  // [100663296, ...      ) wb bf16 | bnbuf | xmean | qm | km | topki | dflag
  char* W = (char*)d_ws;
  bf16*  xhat_t = (bf16*)(W);
  bf16*  xres   = (bf16*)(W);
  bf16*  x0t    = (bf16*)(W + 16777216);
  bf16*  qkv    = (bf16*)(W + 33554432);      // 50,331,648 B
  bf16*  msg    = (bf16*)(W + 83886080);
  bf16*  y1     = (bf16*)(W + 33554432);      // 33,554,432 B (one batch)
  bf16*  y2     = (bf16*)(W + 67108864);      // 33,554,432 B
  char*  S      = W + 100663296;
  bf16*  wb     = (bf16*)(S);             // 795648 elems; rows 0..767 = [768][256] qkv W
  bf16*  wmb    = wb + 196608;
  bf16*  w1b    = wb + 262144;
  bf16*  w2b    = wb + 524288;
  bf16*  wdwb   = wb + 786432;
  float* bnbuf  = (float*)(S + 1591296);  // 5376 floats
  float* xmean  = (float*)(S + 1612800);
  float* qm     = (float*)(S + 2137088);
  float* km     = (float*)(S + 2661376);
  int*   topki  = (int*)(S + 3185664);
  int*   dflag  = (int*)(S + 3202048);

  detect_kernel<<<1, 64, 0, stream>>>(d_in[0], dflag);

  stage_dtype_pre<bf16>(0, d_in, stream, dflag, wb, bnbuf, xhat_t, x0t, xmean, qm, km);
  stage_dtype_pre<float>(1, d_in, stream, dflag, wb, bnbuf, xhat_t, x0t, xmean, qm, km);

  // merged qkv GEMM: [32768][256] x [768][256]^T -> qkv[32768][768]
  mfma_gemm<0><<<dim3(256, 6), 256, 0, stream>>>(dflag,
      xhat_t, wb, (void*)qkv, 0, nullptr, nullptr, nullptr, 32768, 768, 256);

  topk_kernel<<<dim3(256, 2), 256, 0, stream>>>(qm, km, topki);
  attn_kernel<<<dim3(256, 2), 256, 0, stream>>>(qkv, topki, msg);

  // merge + bias + residual: xres[n][c] (overwrites dead xhat_t)
  mfma_gemm<1><<<dim3(256, 2), 256, 0, stream>>>(dflag,
      msg, wmb, (void*)xres, 0, x0t, bnbuf + 5120, nullptr, 32768, 256, 256);

  // MLP tail per batch
  for (int b = 0; b < 2; ++b) {
    bf16* xres_b = xres + (long)b * 4194304;
    mfma_gemm<2><<<dim3(128, 8), 256, 0, stream>>>(dflag,
        xres_b, w1b, (void*)y1, 0, nullptr, bnbuf + 512, bnbuf + 1536, 16384, 1024, 256);
    dwconv_kernel<<<16384, 256, 0, stream>>>(y1, wdwb, bnbuf + 2560, bnbuf + 3584, y2);
    mfma_gemm<3><<<dim3(128, 2), 256, 0, stream>>>(dflag,
        y2, w2b, d_out, (long)b * 4194304, xres_b,
        bnbuf + 4608, bnbuf + 4864, 16384, 256, 1024);
  }
}